// Round 10
// baseline (402.900 us; speedup 1.0000x reference)
//
#include <hip/hip_runtime.h>

#define N_NODES 100000
#define N_EDGES 1600000
#define D_FEAT  128

#define SCAN_CHUNK 1024
#define N_CHUNKS   ((N_NODES + SCAN_CHUNK - 1) / SCAN_CHUNK)   // 98

// ===========================================================================
// CSR path: histogram -> scan -> finalize(base+cursor) -> scatter -> pull
// ===========================================================================

// ---- 1) in-degree histogram (int atomics; deg 400KB, L2-resident) ---------
__global__ void histogram(const int* __restrict__ dst, int* __restrict__ deg) {
    const size_t total4 = N_EDGES / 4;                    // 400000
    size_t tid    = (size_t)blockIdx.x * blockDim.x + threadIdx.x;
    size_t stride = (size_t)gridDim.x * blockDim.x;
    for (size_t i = tid; i < total4; i += stride) {
        int4 d4 = reinterpret_cast<const int4*>(dst)[i];
        atomicAdd(&deg[d4.x], 1);
        atomicAdd(&deg[d4.y], 1);
        atomicAdd(&deg[d4.z], 1);
        atomicAdd(&deg[d4.w], 1);
    }
}

// ---- 2a) per-chunk exclusive scan (chunk = 1024 = 256 thr x 4) ------------
__global__ void scan_chunks(const int* __restrict__ deg,
                            int* __restrict__ offs,
                            int* __restrict__ bsums) {
    __shared__ int lds[256];
    const int b = blockIdx.x, t = threadIdx.x;
    const int base = b * SCAN_CHUNK + t * 4;
    int v0 = (base + 0 < N_NODES) ? deg[base + 0] : 0;
    int v1 = (base + 1 < N_NODES) ? deg[base + 1] : 0;
    int v2 = (base + 2 < N_NODES) ? deg[base + 2] : 0;
    int v3 = (base + 3 < N_NODES) ? deg[base + 3] : 0;
    const int s = v0 + v1 + v2 + v3;
    lds[t] = s;
    __syncthreads();
    int x = s;
    for (int off = 1; off < 256; off <<= 1) {
        int y = (t >= off) ? lds[t - off] : 0;
        __syncthreads();
        x += y;
        lds[t] = x;
        __syncthreads();
    }
    if (t == 255) bsums[b] = x;          // chunk total
    int excl = x - s;                    // exclusive prefix within chunk
    if (base + 0 < N_NODES) offs[base + 0] = excl;  excl += v0;
    if (base + 1 < N_NODES) offs[base + 1] = excl;  excl += v1;
    if (base + 2 < N_NODES) offs[base + 2] = excl;  excl += v2;
    if (base + 3 < N_NODES) offs[base + 3] = excl;
}

// ---- 2b) exclusive scan of the 98 chunk sums (single block) ---------------
__global__ void scan_bsums(int* __restrict__ bsums) {
    __shared__ int lds[128];
    const int t = threadIdx.x;           // 128 threads
    int v = (t < N_CHUNKS) ? bsums[t] : 0;
    lds[t] = v;
    __syncthreads();
    int x = v;
    for (int off = 1; off < 128; off <<= 1) {
        int y = (t >= off) ? lds[t - off] : 0;
        __syncthreads();
        x += y;
        lds[t] = x;
        __syncthreads();
    }
    if (t < N_CHUNKS) bsums[t] = x - v;  // exclusive
}

// ---- 2c) finalize: absolute base into offs AND cursor ---------------------
// After this, build_lists needs exactly ONE atomic per edge.
__global__ void finalize(int* __restrict__ offs,
                         const int* __restrict__ bsums,
                         int* __restrict__ cursor) {
    size_t tid    = (size_t)blockIdx.x * blockDim.x + threadIdx.x;
    size_t stride = (size_t)gridDim.x * blockDim.x;
    for (size_t i = tid; i < N_NODES; i += stride) {
        const int abs_base = offs[i] + bsums[i >> 10];    // SCAN_CHUNK = 1024
        offs[i]   = abs_base;
        cursor[i] = abs_base;
    }
}

// ---- 3) bucket-scatter: one atomic per edge (cursor holds absolute pos) ---
__global__ void build_lists(const int* __restrict__ src,
                            const int* __restrict__ dst,
                            int* __restrict__ cursor,
                            int* __restrict__ edge_list) {
    const size_t total4 = N_EDGES / 4;                    // 400000
    size_t tid    = (size_t)blockIdx.x * blockDim.x + threadIdx.x;
    size_t stride = (size_t)gridDim.x * blockDim.x;
    for (size_t i = tid; i < total4; i += stride) {
        int4 d4 = reinterpret_cast<const int4*>(dst)[i];
        int4 s4 = reinterpret_cast<const int4*>(src)[i];
        edge_list[atomicAdd(&cursor[d4.x], 1)] = s4.x;
        edge_list[atomicAdd(&cursor[d4.y], 1)] = s4.y;
        edge_list[atomicAdd(&cursor[d4.z], 1)] = s4.z;
        edge_list[atomicAdd(&cursor[d4.w], 1)] = s4.w;
    }
}

// ---- 4) pull aggregation: half-wave per node, float4/lane, 4-deep MLP -----
__global__ void __launch_bounds__(256)
aggregate(const float* __restrict__ feat,
          const int*   __restrict__ edge_list,
          const int*   __restrict__ offs,     // absolute bases (finalized)
          const int*   __restrict__ deg,
          float*       __restrict__ out) {
    const size_t gtid = (size_t)blockIdx.x * blockDim.x + threadIdx.x;
    const int node = (int)(gtid >> 5);
    const int lane = threadIdx.x & 31;
    if (node >= N_NODES) return;

    const int base = offs[node];
    const int d    = deg[node];
    const size_t col = (size_t)lane * 4;

    float4 acc0 = make_float4(0.f, 0.f, 0.f, 0.f);
    float4 acc1 = make_float4(0.f, 0.f, 0.f, 0.f);
    float4 acc2 = make_float4(0.f, 0.f, 0.f, 0.f);
    float4 acc3 = make_float4(0.f, 0.f, 0.f, 0.f);

    int j = 0;
    for (; j + 3 < d; j += 4) {          // 4 independent load chains
        const int s0 = edge_list[base + j];
        const int s1 = edge_list[base + j + 1];
        const int s2 = edge_list[base + j + 2];
        const int s3 = edge_list[base + j + 3];
        float4 a = *reinterpret_cast<const float4*>(feat + (size_t)s0 * D_FEAT + col);
        float4 b = *reinterpret_cast<const float4*>(feat + (size_t)s1 * D_FEAT + col);
        float4 c = *reinterpret_cast<const float4*>(feat + (size_t)s2 * D_FEAT + col);
        float4 e = *reinterpret_cast<const float4*>(feat + (size_t)s3 * D_FEAT + col);
        acc0.x += a.x; acc0.y += a.y; acc0.z += a.z; acc0.w += a.w;
        acc1.x += b.x; acc1.y += b.y; acc1.z += b.z; acc1.w += b.w;
        acc2.x += c.x; acc2.y += c.y; acc2.z += c.z; acc2.w += c.w;
        acc3.x += e.x; acc3.y += e.y; acc3.z += e.z; acc3.w += e.w;
    }
    for (; j < d; ++j) {
        const int s0 = edge_list[base + j];
        float4 a = *reinterpret_cast<const float4*>(feat + (size_t)s0 * D_FEAT + col);
        acc0.x += a.x; acc0.y += a.y; acc0.z += a.z; acc0.w += a.w;
    }
    const float inv = 1.0f / (float)max(d, 1);
    float4 r;
    r.x = (acc0.x + acc1.x + acc2.x + acc3.x) * inv;
    r.y = (acc0.y + acc1.y + acc2.y + acc3.y) * inv;
    r.z = (acc0.z + acc1.z + acc2.z + acc3.z) * inv;
    r.w = (acc0.w + acc1.w + acc2.w + acc3.w) * inv;
    *reinterpret_cast<float4*>(out + (size_t)node * D_FEAT + col) = r;
}

// ===========================================================================
// Fallback path (atomic scatter) — only if ws_size is too small for CSR
// ===========================================================================
__global__ void zero_out_deg(float* __restrict__ out, float* __restrict__ deg) {
    const size_t total4 = (size_t)N_NODES * D_FEAT / 4;
    size_t tid    = (size_t)blockIdx.x * blockDim.x + threadIdx.x;
    size_t stride = (size_t)gridDim.x * blockDim.x;
    float4 z = make_float4(0.f, 0.f, 0.f, 0.f);
    for (size_t i = tid; i < total4; i += stride)
        reinterpret_cast<float4*>(out)[i] = z;
    for (size_t i = tid; i < N_NODES; i += stride)
        deg[i] = 0.f;
}

__global__ void scatter_atomic(const float* __restrict__ feat,
                               const int*   __restrict__ src,
                               const int*   __restrict__ dst,
                               float*       __restrict__ out,
                               float*       __restrict__ deg) {
    const size_t total  = (size_t)N_EDGES * 32;
    size_t tid    = (size_t)blockIdx.x * blockDim.x + threadIdx.x;
    size_t stride = (size_t)gridDim.x * blockDim.x;
    for (size_t i = tid; i < total; i += stride) {
        const int e = (int)(i >> 5);
        const int c = (int)(i & 31);
        const int s = src[e];
        const int d = dst[e];
        float4 v = reinterpret_cast<const float4*>(feat + (size_t)s * D_FEAT)[c];
        float* o = out + (size_t)d * D_FEAT + (size_t)c * 4;
        unsafeAtomicAdd(o + 0, v.x);
        unsafeAtomicAdd(o + 1, v.y);
        unsafeAtomicAdd(o + 2, v.z);
        unsafeAtomicAdd(o + 3, v.w);
        if (c == 0) unsafeAtomicAdd(deg + d, 1.0f);
    }
}

__global__ void div_mean(float* __restrict__ out, const float* __restrict__ deg) {
    const size_t total4 = (size_t)N_NODES * D_FEAT / 4;
    size_t tid    = (size_t)blockIdx.x * blockDim.x + threadIdx.x;
    size_t stride = (size_t)gridDim.x * blockDim.x;
    for (size_t i = tid; i < total4; i += stride) {
        const float inv = 1.0f / fmaxf(deg[i >> 5], 1.0f);
        float4 v = reinterpret_cast<float4*>(out)[i];
        v.x *= inv; v.y *= inv; v.z *= inv; v.w *= inv;
        reinterpret_cast<float4*>(out)[i] = v;
    }
}

// ===========================================================================
extern "C" void kernel_launch(void* const* d_in, const int* in_sizes, int n_in,
                              void* d_out, int out_size, void* d_ws, size_t ws_size,
                              hipStream_t stream) {
    const float* feat = (const float*)d_in[0];
    const int*   src  = (const int*)d_in[1];
    const int*   dst  = (const int*)d_in[2];
    float* out = (float*)d_out;

    // CSR workspace (ints): deg[N] | offs[N] | cursor[N] | bsums[128] | edge_list[E]
    const size_t need = ((size_t)3 * N_NODES + 128 + N_EDGES) * sizeof(int);

    if (ws_size >= need) {
        int* deg       = (int*)d_ws;
        int* offs      = deg  + N_NODES;
        int* cursor    = offs + N_NODES;
        int* bsums     = cursor + N_NODES;
        int* edge_list = bsums + 128;

        hipMemsetAsync(deg, 0, (size_t)N_NODES * sizeof(int), stream);
        histogram   <<<1563,     256, 0, stream>>>(dst, deg);
        scan_chunks <<<N_CHUNKS, 256, 0, stream>>>(deg, offs, bsums);
        scan_bsums  <<<1,        128, 0, stream>>>(bsums);
        finalize    <<<391,      256, 0, stream>>>(offs, bsums, cursor);
        build_lists <<<1563,     256, 0, stream>>>(src, dst, cursor, edge_list);
        // 100000 nodes x 32 threads = 3.2M threads -> 12500 blocks of 256
        aggregate   <<<12500,    256, 0, stream>>>(feat, edge_list, offs, deg, out);
    } else {
        float* fdeg = (float*)d_ws;
        zero_out_deg  <<<2048, 256, 0, stream>>>(out, fdeg);
        scatter_atomic<<<8192, 256, 0, stream>>>(feat, src, dst, out, fdeg);
        div_mean      <<<2048, 256, 0, stream>>>(out, fdeg);
    }
}

// Round 11
// 321.423 us; speedup vs baseline: 1.2535x; 1.2535x over previous
//
#include <hip/hip_runtime.h>

#define N_NODES 100000
#define N_EDGES 1600000
#define D_FEAT  128

// ===========================================================================
// Linked-list path: memset(head=-1) -> link_build -> pull aggregate
//
// Replaces the CSR build (histogram+scan+finalize+bucket-scatter). Rationale
// (round-10 rocprof): bucket-scatter did 1.6M random 4B stores -> 108 MB of
// HBM writes (17x amplification) + 1.6M returning atomics = 137 us. Here the
// per-edge write (next[e]) is COALESCED int4; only the atomicExch remains.
// ===========================================================================

// ---- 1) build chains: head[d] -> newest edge, next[e] -> previous ---------
__global__ void link_build(const int* __restrict__ dst,
                           int* __restrict__ head,
                           int* __restrict__ next) {
    const size_t total4 = N_EDGES / 4;                    // 400000
    size_t tid    = (size_t)blockIdx.x * blockDim.x + threadIdx.x;
    size_t stride = (size_t)gridDim.x * blockDim.x;
    for (size_t i = tid; i < total4; i += stride) {
        int4 d4 = reinterpret_cast<const int4*>(dst)[i];
        const int e0 = (int)(i << 2);
        int4 o;                                            // previous heads
        o.x = atomicExch(&head[d4.x], e0 + 0);
        o.y = atomicExch(&head[d4.y], e0 + 1);
        o.z = atomicExch(&head[d4.z], e0 + 2);
        o.w = atomicExch(&head[d4.w], e0 + 3);
        reinterpret_cast<int4*>(next)[i] = o;              // coalesced 16B
    }
}

// ---- 2) pull aggregation: half-wave (32 lanes) per node, float4 per lane --
// Chain walk: next[e]/src[e] are half-wave-uniform -> broadcast loads
// (1 transaction/step). Degree counted during the walk (no histogram).
__global__ void __launch_bounds__(256)
aggregate_ll(const float* __restrict__ feat,
             const int*   __restrict__ src,
             const int*   __restrict__ head,
             const int*   __restrict__ next,
             float*       __restrict__ out) {
    const size_t gtid = (size_t)blockIdx.x * blockDim.x + threadIdx.x;
    const int node = (int)(gtid >> 5);
    const int lane = threadIdx.x & 31;
    if (node >= N_NODES) return;

    const size_t col = (size_t)lane * 4;
    float4 acc = make_float4(0.f, 0.f, 0.f, 0.f);
    int c = 0;

    int e = head[node];
    while (e >= 0) {
        const int en = next[e];                            // serial chain dep
        const int s  = src[e];                             // off-chain
        const float4 a = *reinterpret_cast<const float4*>(
            feat + (size_t)s * D_FEAT + col);
        acc.x += a.x; acc.y += a.y; acc.z += a.z; acc.w += a.w;
        ++c;
        e = en;
    }
    const float inv = 1.0f / (float)max(c, 1);
    float4 r;
    r.x = acc.x * inv; r.y = acc.y * inv;
    r.z = acc.z * inv; r.w = acc.w * inv;
    *reinterpret_cast<float4*>(out + (size_t)node * D_FEAT + col) = r;
}

// ===========================================================================
// Fallback path (atomic scatter) — only if ws_size is too small
// ===========================================================================
__global__ void zero_out_deg(float* __restrict__ out, float* __restrict__ deg) {
    const size_t total4 = (size_t)N_NODES * D_FEAT / 4;
    size_t tid    = (size_t)blockIdx.x * blockDim.x + threadIdx.x;
    size_t stride = (size_t)gridDim.x * blockDim.x;
    float4 z = make_float4(0.f, 0.f, 0.f, 0.f);
    for (size_t i = tid; i < total4; i += stride)
        reinterpret_cast<float4*>(out)[i] = z;
    for (size_t i = tid; i < N_NODES; i += stride)
        deg[i] = 0.f;
}

__global__ void scatter_atomic(const float* __restrict__ feat,
                               const int*   __restrict__ src,
                               const int*   __restrict__ dst,
                               float*       __restrict__ out,
                               float*       __restrict__ deg) {
    const size_t total  = (size_t)N_EDGES * 32;
    size_t tid    = (size_t)blockIdx.x * blockDim.x + threadIdx.x;
    size_t stride = (size_t)gridDim.x * blockDim.x;
    for (size_t i = tid; i < total; i += stride) {
        const int e = (int)(i >> 5);
        const int c = (int)(i & 31);
        const int s = src[e];
        const int d = dst[e];
        float4 v = reinterpret_cast<const float4*>(feat + (size_t)s * D_FEAT)[c];
        float* o = out + (size_t)d * D_FEAT + (size_t)c * 4;
        unsafeAtomicAdd(o + 0, v.x);
        unsafeAtomicAdd(o + 1, v.y);
        unsafeAtomicAdd(o + 2, v.z);
        unsafeAtomicAdd(o + 3, v.w);
        if (c == 0) unsafeAtomicAdd(deg + d, 1.0f);
    }
}

__global__ void div_mean(float* __restrict__ out, const float* __restrict__ deg) {
    const size_t total4 = (size_t)N_NODES * D_FEAT / 4;
    size_t tid    = (size_t)blockIdx.x * blockDim.x + threadIdx.x;
    size_t stride = (size_t)gridDim.x * blockDim.x;
    for (size_t i = tid; i < total4; i += stride) {
        const float inv = 1.0f / fmaxf(deg[i >> 5], 1.0f);
        float4 v = reinterpret_cast<float4*>(out)[i];
        v.x *= inv; v.y *= inv; v.z *= inv; v.w *= inv;
        reinterpret_cast<float4*>(out)[i] = v;
    }
}

// ===========================================================================
extern "C" void kernel_launch(void* const* d_in, const int* in_sizes, int n_in,
                              void* d_out, int out_size, void* d_ws, size_t ws_size,
                              hipStream_t stream) {
    const float* feat = (const float*)d_in[0];
    const int*   src  = (const int*)d_in[1];
    const int*   dst  = (const int*)d_in[2];
    float* out = (float*)d_out;

    // Workspace (ints): head[N] | next[E]  = 6.8 MB
    const size_t need = ((size_t)N_NODES + N_EDGES) * sizeof(int);

    if (ws_size >= need) {
        int* head = (int*)d_ws;
        int* next = head + N_NODES;

        hipMemsetAsync(head, 0xFF, (size_t)N_NODES * sizeof(int), stream); // -1
        link_build  <<<1563,  256, 0, stream>>>(dst, head, next);
        // 100000 nodes x 32 threads = 3.2M threads -> 12500 blocks of 256
        aggregate_ll<<<12500, 256, 0, stream>>>(feat, src, head, next, out);
    } else {
        float* fdeg = (float*)d_ws;
        zero_out_deg  <<<2048, 256, 0, stream>>>(out, fdeg);
        scatter_atomic<<<8192, 256, 0, stream>>>(feat, src, dst, out, fdeg);
        div_mean      <<<2048, 256, 0, stream>>>(out, fdeg);
    }
}

// Round 12
// 316.574 us; speedup vs baseline: 1.2727x; 1.0153x over previous
//
#include <hip/hip_runtime.h>

#define N_NODES 100000
#define N_EDGES 1600000
#define D_FEAT  128

// ===========================================================================
// Linked-list path, v2: TWO chains per node (edge-parity split).
//
// Round-11 evidence: both CSR bucket-scatter (137us) and 1-chain atomicExch
// build (146us) hit the same ~12 G returning-atomics/s wall -> the cost is
// the random returning atomic, not the write pattern. If the wall is
// same-address serialization (16 avg collisions), 2x addresses halves it.
// Aggregate walks both chains concurrently: serial depth 16->8, 2-way MLP.
// ===========================================================================

// ---- 1) build chains: head[2d+parity] -> newest edge of that parity -------
__global__ void link_build2(const int* __restrict__ dst,
                            int* __restrict__ head,
                            int* __restrict__ next) {
    const size_t total4 = N_EDGES / 4;                    // 400000
    size_t tid    = (size_t)blockIdx.x * blockDim.x + threadIdx.x;
    size_t stride = (size_t)gridDim.x * blockDim.x;
    for (size_t i = tid; i < total4; i += stride) {
        int4 d4 = reinterpret_cast<const int4*>(dst)[i];
        const int e0 = (int)(i << 2);                     // e0 is even
        int4 o;                                           // previous heads
        o.x = atomicExch(&head[2 * d4.x + 0], e0 + 0);    // even chain
        o.y = atomicExch(&head[2 * d4.y + 1], e0 + 1);    // odd chain
        o.z = atomicExch(&head[2 * d4.z + 0], e0 + 2);    // even chain
        o.w = atomicExch(&head[2 * d4.w + 1], e0 + 3);    // odd chain
        reinterpret_cast<int4*>(next)[i] = o;             // coalesced 16B
    }
}

// ---- 2) pull aggregation: half-wave per node, float4/lane, 2 chains -------
__global__ void __launch_bounds__(256)
aggregate_ll2(const float* __restrict__ feat,
              const int*   __restrict__ src,
              const int*   __restrict__ head,
              const int*   __restrict__ next,
              float*       __restrict__ out) {
    const size_t gtid = (size_t)blockIdx.x * blockDim.x + threadIdx.x;
    const int node = (int)(gtid >> 5);
    const int lane = threadIdx.x & 31;
    if (node >= N_NODES) return;

    const size_t col = (size_t)lane * 4;
    float4 accA = make_float4(0.f, 0.f, 0.f, 0.f);
    float4 accB = make_float4(0.f, 0.f, 0.f, 0.f);
    int cA = 0, cB = 0;

    const int2 h = *reinterpret_cast<const int2*>(head + 2 * (size_t)node);
    int eA = h.x, eB = h.y;

    // joint walk: two independent dependency chains (ILP on next/src/feat)
    while (eA >= 0 && eB >= 0) {
        const int nA = next[eA];
        const int nB = next[eB];
        const int sA = src[eA];
        const int sB = src[eB];
        const float4 a = *reinterpret_cast<const float4*>(
            feat + (size_t)sA * D_FEAT + col);
        const float4 b = *reinterpret_cast<const float4*>(
            feat + (size_t)sB * D_FEAT + col);
        accA.x += a.x; accA.y += a.y; accA.z += a.z; accA.w += a.w;
        accB.x += b.x; accB.y += b.y; accB.z += b.z; accB.w += b.w;
        ++cA; ++cB;
        eA = nA; eB = nB;
    }
    while (eA >= 0) {                                     // drain chain A
        const int nA = next[eA];
        const int sA = src[eA];
        const float4 a = *reinterpret_cast<const float4*>(
            feat + (size_t)sA * D_FEAT + col);
        accA.x += a.x; accA.y += a.y; accA.z += a.z; accA.w += a.w;
        ++cA;
        eA = nA;
    }
    while (eB >= 0) {                                     // drain chain B
        const int nB = next[eB];
        const int sB = src[eB];
        const float4 b = *reinterpret_cast<const float4*>(
            feat + (size_t)sB * D_FEAT + col);
        accB.x += b.x; accB.y += b.y; accB.z += b.z; accB.w += b.w;
        ++cB;
        eB = nB;
    }
    const float inv = 1.0f / (float)max(cA + cB, 1);
    float4 r;
    r.x = (accA.x + accB.x) * inv;
    r.y = (accA.y + accB.y) * inv;
    r.z = (accA.z + accB.z) * inv;
    r.w = (accA.w + accB.w) * inv;
    *reinterpret_cast<float4*>(out + (size_t)node * D_FEAT + col) = r;
}

// ===========================================================================
// Fallback path (atomic scatter) — only if ws_size is too small
// ===========================================================================
__global__ void zero_out_deg(float* __restrict__ out, float* __restrict__ deg) {
    const size_t total4 = (size_t)N_NODES * D_FEAT / 4;
    size_t tid    = (size_t)blockIdx.x * blockDim.x + threadIdx.x;
    size_t stride = (size_t)gridDim.x * blockDim.x;
    float4 z = make_float4(0.f, 0.f, 0.f, 0.f);
    for (size_t i = tid; i < total4; i += stride)
        reinterpret_cast<float4*>(out)[i] = z;
    for (size_t i = tid; i < N_NODES; i += stride)
        deg[i] = 0.f;
}

__global__ void scatter_atomic(const float* __restrict__ feat,
                               const int*   __restrict__ src,
                               const int*   __restrict__ dst,
                               float*       __restrict__ out,
                               float*       __restrict__ deg) {
    const size_t total  = (size_t)N_EDGES * 32;
    size_t tid    = (size_t)blockIdx.x * blockDim.x + threadIdx.x;
    size_t stride = (size_t)gridDim.x * blockDim.x;
    for (size_t i = tid; i < total; i += stride) {
        const int e = (int)(i >> 5);
        const int c = (int)(i & 31);
        const int s = src[e];
        const int d = dst[e];
        float4 v = reinterpret_cast<const float4*>(feat + (size_t)s * D_FEAT)[c];
        float* o = out + (size_t)d * D_FEAT + (size_t)c * 4;
        unsafeAtomicAdd(o + 0, v.x);
        unsafeAtomicAdd(o + 1, v.y);
        unsafeAtomicAdd(o + 2, v.z);
        unsafeAtomicAdd(o + 3, v.w);
        if (c == 0) unsafeAtomicAdd(deg + d, 1.0f);
    }
}

__global__ void div_mean(float* __restrict__ out, const float* __restrict__ deg) {
    const size_t total4 = (size_t)N_NODES * D_FEAT / 4;
    size_t tid    = (size_t)blockIdx.x * blockDim.x + threadIdx.x;
    size_t stride = (size_t)gridDim.x * blockDim.x;
    for (size_t i = tid; i < total4; i += stride) {
        const float inv = 1.0f / fmaxf(deg[i >> 5], 1.0f);
        float4 v = reinterpret_cast<float4*>(out)[i];
        v.x *= inv; v.y *= inv; v.z *= inv; v.w *= inv;
        reinterpret_cast<float4*>(out)[i] = v;
    }
}

// ===========================================================================
extern "C" void kernel_launch(void* const* d_in, const int* in_sizes, int n_in,
                              void* d_out, int out_size, void* d_ws, size_t ws_size,
                              hipStream_t stream) {
    const float* feat = (const float*)d_in[0];
    const int*   src  = (const int*)d_in[1];
    const int*   dst  = (const int*)d_in[2];
    float* out = (float*)d_out;

    // Workspace (ints): head[2N] | next[E]  = 7.2 MB
    const size_t need = ((size_t)2 * N_NODES + N_EDGES) * sizeof(int);

    if (ws_size >= need) {
        int* head = (int*)d_ws;
        int* next = head + 2 * (size_t)N_NODES;

        hipMemsetAsync(head, 0xFF, (size_t)2 * N_NODES * sizeof(int), stream);
        link_build2  <<<1563,  256, 0, stream>>>(dst, head, next);
        // 100000 nodes x 32 threads = 3.2M threads -> 12500 blocks of 256
        aggregate_ll2<<<12500, 256, 0, stream>>>(feat, src, head, next, out);
    } else {
        float* fdeg = (float*)d_ws;
        zero_out_deg  <<<2048, 256, 0, stream>>>(out, fdeg);
        scatter_atomic<<<8192, 256, 0, stream>>>(feat, src, dst, out, fdeg);
        div_mean      <<<2048, 256, 0, stream>>>(out, fdeg);
    }
}

// Round 13
// 251.990 us; speedup vs baseline: 1.5989x; 1.2563x over previous
//
#include <hip/hip_runtime.h>

#define N_NODES 100000
#define N_EDGES 1600000
#define D_FEAT  128

#define NBUCK   ((N_NODES + 255) >> 8)        // 391 buckets of 256 nodes
#define CAP     8192                           // max edges/bucket staged in LDS
                                               // (binomial mean 4096, sigma 64 -> 64 sigma guard)

// ===========================================================================
// Two-level bucket-sort CSR build: zero per-edge global atomics.
// Evidence (r10/r12): 1.6M random returning global atomics = ~140us wall
// regardless of address count or write pattern. Here: per-edge work uses LDS
// atomics only; global atomics = ~100K block-level reservations.
// ===========================================================================

// ---- k1: coarse histogram over buckets (dst >> 8) -------------------------
__global__ void k1_coarse_hist(const int* __restrict__ dst,
                               int* __restrict__ ghist) {
    __shared__ int lh[NBUCK];
    for (int t = threadIdx.x; t < NBUCK; t += blockDim.x) lh[t] = 0;
    __syncthreads();
    const size_t total4 = N_EDGES / 4;
    size_t tid    = (size_t)blockIdx.x * blockDim.x + threadIdx.x;
    size_t stride = (size_t)gridDim.x * blockDim.x;
    for (size_t i = tid; i < total4; i += stride) {
        int4 d4 = reinterpret_cast<const int4*>(dst)[i];
        atomicAdd(&lh[d4.x >> 8], 1);
        atomicAdd(&lh[d4.y >> 8], 1);
        atomicAdd(&lh[d4.z >> 8], 1);
        atomicAdd(&lh[d4.w >> 8], 1);
    }
    __syncthreads();
    for (int t = threadIdx.x; t < NBUCK; t += blockDim.x)
        if (lh[t]) atomicAdd(&ghist[t], lh[t]);
}

// ---- k2: exclusive scan of 391 bucket counts (1 block, 512 thr) -----------
__global__ void k2_scan(const int* __restrict__ ghist,
                        int* __restrict__ base,
                        int* __restrict__ gcursor) {
    __shared__ int ls[512];
    const int t = threadIdx.x;
    int v = (t < NBUCK) ? ghist[t] : 0;
    ls[t] = v;
    __syncthreads();
    int x = v;
    for (int off = 1; off < 512; off <<= 1) {
        int y = (t >= off) ? ls[t - off] : 0;
        __syncthreads();
        x += y;
        ls[t] = x;
        __syncthreads();
    }
    if (t < NBUCK) {
        base[t]    = x - v;                    // exclusive
        gcursor[t] = x - v;
    }
}

// ---- k3: bucket-scatter with block-level reservation ----------------------
// Per block: LDS-count its contiguous edge range, ONE global atomicAdd per
// touched bucket, then write packed (src | dlo<<17) to reserved slots.
__global__ void k3_bucket(const int* __restrict__ src,
                          const int* __restrict__ dst,
                          int* __restrict__ gcursor,
                          int* __restrict__ packed) {
    __shared__ int lh[NBUCK];
    __shared__ int lcur[NBUCK];
    const int total4  = N_EDGES / 4;                       // 400000
    const int chunk4  = (total4 + gridDim.x - 1) / gridDim.x;
    const int start4  = blockIdx.x * chunk4;
    const int end4    = min(total4, start4 + chunk4);

    for (int t = threadIdx.x; t < NBUCK; t += blockDim.x) lh[t] = 0;
    __syncthreads();
    // pass A: count
    for (int i = start4 + threadIdx.x; i < end4; i += blockDim.x) {
        int4 d4 = reinterpret_cast<const int4*>(dst)[i];
        atomicAdd(&lh[d4.x >> 8], 1);
        atomicAdd(&lh[d4.y >> 8], 1);
        atomicAdd(&lh[d4.z >> 8], 1);
        atomicAdd(&lh[d4.w >> 8], 1);
    }
    __syncthreads();
    // reserve: one global atomic per (block, non-empty bucket)
    for (int t = threadIdx.x; t < NBUCK; t += blockDim.x)
        lcur[t] = lh[t] ? atomicAdd(&gcursor[t], lh[t]) : 0;
    __syncthreads();
    // pass B: write packed into reserved slots (LDS cursor atomics)
    for (int i = start4 + threadIdx.x; i < end4; i += blockDim.x) {
        int4 d4 = reinterpret_cast<const int4*>(dst)[i];
        int4 s4 = reinterpret_cast<const int4*>(src)[i];
        int slot;
        slot = atomicAdd(&lcur[d4.x >> 8], 1);
        packed[slot] = s4.x | ((d4.x & 255) << 17);
        slot = atomicAdd(&lcur[d4.y >> 8], 1);
        packed[slot] = s4.y | ((d4.y & 255) << 17);
        slot = atomicAdd(&lcur[d4.z >> 8], 1);
        packed[slot] = s4.z | ((d4.z & 255) << 17);
        slot = atomicAdd(&lcur[d4.w >> 8], 1);
        packed[slot] = s4.w | ((d4.w & 255) << 17);
    }
}

// ---- k4: fine CSR within each bucket, in place ----------------------------
// Stage bucket's packed edges in LDS (no alias race), 256-counter LDS
// hist+scan, write deg/offs (contiguous), scatter src over same range.
__global__ void __launch_bounds__(256)
k4_fine(const int* __restrict__ ghist,
        const int* __restrict__ base,
        int* __restrict__ packed,
        int* __restrict__ deg,
        int* __restrict__ offs) {
    __shared__ int lpk[CAP];
    __shared__ int lcnt[256];
    __shared__ int lscan[256];
    __shared__ int lcur[256];
    const int b  = blockIdx.x;
    const int t  = threadIdx.x;
    const int gb = base[b];
    int nb = ghist[b];
    if (nb > CAP) nb = CAP;                    // impossible; LDS-OOB guard

    lcnt[t] = 0;
    __syncthreads();
    for (int idx = t; idx < nb; idx += 256) {  // stage + count
        const int p = packed[gb + idx];
        lpk[idx] = p;
        atomicAdd(&lcnt[(p >> 17) & 255], 1);
    }
    __syncthreads();
    lscan[t] = lcnt[t];
    __syncthreads();
    int x = lcnt[t];
    for (int off = 1; off < 256; off <<= 1) {
        int y = (t >= off) ? lscan[t - off] : 0;
        __syncthreads();
        x += y;
        lscan[t] = x;
        __syncthreads();
    }
    const int excl = x - lcnt[t];
    const int node = (b << 8) + t;
    if (node < N_NODES) {
        deg[node]  = lcnt[t];
        offs[node] = gb + excl;
    }
    lcur[t] = excl;
    __syncthreads();
    for (int idx = t; idx < nb; idx += 256) {  // in-place permuted write
        const int p    = lpk[idx];
        const int slot = atomicAdd(&lcur[(p >> 17) & 255], 1);
        packed[gb + slot] = p & 0x1FFFF;       // pure src id = final edge_list
    }
}

// ---- k5: pull aggregation (CSR, half-wave/node, float4/lane, 4-deep) ------
__global__ void __launch_bounds__(256)
aggregate(const float* __restrict__ feat,
          const int*   __restrict__ edge_list,
          const int*   __restrict__ offs,
          const int*   __restrict__ deg,
          float*       __restrict__ out) {
    const size_t gtid = (size_t)blockIdx.x * blockDim.x + threadIdx.x;
    const int node = (int)(gtid >> 5);
    const int lane = threadIdx.x & 31;
    if (node >= N_NODES) return;

    const int base = offs[node];
    const int d    = deg[node];
    const size_t col = (size_t)lane * 4;

    float4 acc0 = make_float4(0.f, 0.f, 0.f, 0.f);
    float4 acc1 = make_float4(0.f, 0.f, 0.f, 0.f);
    float4 acc2 = make_float4(0.f, 0.f, 0.f, 0.f);
    float4 acc3 = make_float4(0.f, 0.f, 0.f, 0.f);

    int j = 0;
    for (; j + 3 < d; j += 4) {                // 4 independent load chains
        const int s0 = edge_list[base + j];
        const int s1 = edge_list[base + j + 1];
        const int s2 = edge_list[base + j + 2];
        const int s3 = edge_list[base + j + 3];
        float4 a = *reinterpret_cast<const float4*>(feat + (size_t)s0 * D_FEAT + col);
        float4 b = *reinterpret_cast<const float4*>(feat + (size_t)s1 * D_FEAT + col);
        float4 c = *reinterpret_cast<const float4*>(feat + (size_t)s2 * D_FEAT + col);
        float4 e = *reinterpret_cast<const float4*>(feat + (size_t)s3 * D_FEAT + col);
        acc0.x += a.x; acc0.y += a.y; acc0.z += a.z; acc0.w += a.w;
        acc1.x += b.x; acc1.y += b.y; acc1.z += b.z; acc1.w += b.w;
        acc2.x += c.x; acc2.y += c.y; acc2.z += c.z; acc2.w += c.w;
        acc3.x += e.x; acc3.y += e.y; acc3.z += e.z; acc3.w += e.w;
    }
    for (; j < d; ++j) {
        const int s0 = edge_list[base + j];
        float4 a = *reinterpret_cast<const float4*>(feat + (size_t)s0 * D_FEAT + col);
        acc0.x += a.x; acc0.y += a.y; acc0.z += a.z; acc0.w += a.w;
    }
    const float inv = 1.0f / (float)max(d, 1);
    float4 r;
    r.x = (acc0.x + acc1.x + acc2.x + acc3.x) * inv;
    r.y = (acc0.y + acc1.y + acc2.y + acc3.y) * inv;
    r.z = (acc0.z + acc1.z + acc2.z + acc3.z) * inv;
    r.w = (acc0.w + acc1.w + acc2.w + acc3.w) * inv;
    *reinterpret_cast<float4*>(out + (size_t)node * D_FEAT + col) = r;
}

// ===========================================================================
// Fallback (atomic scatter) — only if ws_size is too small (never observed)
// ===========================================================================
__global__ void zero_out_deg(float* __restrict__ out, float* __restrict__ deg) {
    const size_t total4 = (size_t)N_NODES * D_FEAT / 4;
    size_t tid    = (size_t)blockIdx.x * blockDim.x + threadIdx.x;
    size_t stride = (size_t)gridDim.x * blockDim.x;
    float4 z = make_float4(0.f, 0.f, 0.f, 0.f);
    for (size_t i = tid; i < total4; i += stride)
        reinterpret_cast<float4*>(out)[i] = z;
    for (size_t i = tid; i < N_NODES; i += stride)
        deg[i] = 0.f;
}

__global__ void scatter_atomic(const float* __restrict__ feat,
                               const int*   __restrict__ src,
                               const int*   __restrict__ dst,
                               float*       __restrict__ out,
                               float*       __restrict__ deg) {
    const size_t total  = (size_t)N_EDGES * 32;
    size_t tid    = (size_t)blockIdx.x * blockDim.x + threadIdx.x;
    size_t stride = (size_t)gridDim.x * blockDim.x;
    for (size_t i = tid; i < total; i += stride) {
        const int e = (int)(i >> 5);
        const int c = (int)(i & 31);
        const int s = src[e];
        const int d = dst[e];
        float4 v = reinterpret_cast<const float4*>(feat + (size_t)s * D_FEAT)[c];
        float* o = out + (size_t)d * D_FEAT + (size_t)c * 4;
        unsafeAtomicAdd(o + 0, v.x);
        unsafeAtomicAdd(o + 1, v.y);
        unsafeAtomicAdd(o + 2, v.z);
        unsafeAtomicAdd(o + 3, v.w);
        if (c == 0) unsafeAtomicAdd(deg + d, 1.0f);
    }
}

__global__ void div_mean(float* __restrict__ out, const float* __restrict__ deg) {
    const size_t total4 = (size_t)N_NODES * D_FEAT / 4;
    size_t tid    = (size_t)blockIdx.x * blockDim.x + threadIdx.x;
    size_t stride = (size_t)gridDim.x * blockDim.x;
    for (size_t i = tid; i < total4; i += stride) {
        const float inv = 1.0f / fmaxf(deg[i >> 5], 1.0f);
        float4 v = reinterpret_cast<float4*>(out)[i];
        v.x *= inv; v.y *= inv; v.z *= inv; v.w *= inv;
        reinterpret_cast<float4*>(out)[i] = v;
    }
}

// ===========================================================================
extern "C" void kernel_launch(void* const* d_in, const int* in_sizes, int n_in,
                              void* d_out, int out_size, void* d_ws, size_t ws_size,
                              hipStream_t stream) {
    const float* feat = (const float*)d_in[0];
    const int*   src  = (const int*)d_in[1];
    const int*   dst  = (const int*)d_in[2];
    float* out = (float*)d_out;

    // Workspace (ints): ghist[512] | base[512] | gcursor[512] | deg[N] |
    //                   offs[N] | packed[E]  (~6.9 MiB)
    const size_t need = ((size_t)1536 + 2 * N_NODES + N_EDGES) * sizeof(int);

    if (ws_size >= need) {
        int* ghist   = (int*)d_ws;
        int* base    = ghist   + 512;
        int* gcursor = base    + 512;
        int* deg     = gcursor + 512;
        int* offs    = deg     + N_NODES;
        int* packed  = offs    + N_NODES;    // doubles as final edge_list

        hipMemsetAsync(ghist, 0, NBUCK * sizeof(int), stream);
        k1_coarse_hist<<<256,   256, 0, stream>>>(dst, ghist);
        k2_scan       <<<1,     512, 0, stream>>>(ghist, base, gcursor);
        k3_bucket     <<<256,   256, 0, stream>>>(src, dst, gcursor, packed);
        k4_fine       <<<NBUCK, 256, 0, stream>>>(ghist, base, packed, deg, offs);
        aggregate     <<<12500, 256, 0, stream>>>(feat, packed, offs, deg, out);
    } else {
        float* fdeg = (float*)d_ws;
        zero_out_deg  <<<2048, 256, 0, stream>>>(out, fdeg);
        scatter_atomic<<<8192, 256, 0, stream>>>(feat, src, dst, out, fdeg);
        div_mean      <<<2048, 256, 0, stream>>>(out, fdeg);
    }
}

// Round 14
// 244.242 us; speedup vs baseline: 1.6496x; 1.0317x over previous
//
#include <hip/hip_runtime.h>

#define N_NODES 100000
#define N_EDGES 1600000
#define D_FEAT  128

#define NBUCK   ((N_NODES + 255) >> 8)        // 391 buckets of 256 nodes
#define CAP     8192                          // k4 LDS stage (mean 4096, 64 sigma guard)
#define CHUNK4  ((N_EDGES / 4 + 255) / 256)   // 1563 int4 per k3 block
#define KCAP    (CHUNK4 * 4)                  // 6252 edges per k3 block

// ===========================================================================
// Build: zero per-edge global atomics AND zero uncoalesced global stores.
// r10/r12: 1.6M random returning atomics = ~140us wall. r13: k3's 1.6M random
// 4B stores = same wall (~uncoalesced line-touch rate). Fix: counting-sort in
// LDS, then ONE coalesced sweep to global (runs of ~16 edges).
// ===========================================================================

// ---- k1: coarse histogram over buckets (dst >> 8), LDS-staged -------------
__global__ void k1_coarse_hist(const int* __restrict__ dst,
                               int* __restrict__ ghist) {
    __shared__ int lh[NBUCK];
    for (int t = threadIdx.x; t < NBUCK; t += blockDim.x) lh[t] = 0;
    __syncthreads();
    const size_t total4 = N_EDGES / 4;
    size_t tid    = (size_t)blockIdx.x * blockDim.x + threadIdx.x;
    size_t stride = (size_t)gridDim.x * blockDim.x;
    for (size_t i = tid; i < total4; i += stride) {
        int4 d4 = reinterpret_cast<const int4*>(dst)[i];
        atomicAdd(&lh[d4.x >> 8], 1);
        atomicAdd(&lh[d4.y >> 8], 1);
        atomicAdd(&lh[d4.z >> 8], 1);
        atomicAdd(&lh[d4.w >> 8], 1);
    }
    __syncthreads();
    for (int t = threadIdx.x; t < NBUCK; t += blockDim.x)
        if (lh[t]) atomicAdd(&ghist[t], lh[t]);
}

// ---- k2: exclusive scan of 391 bucket counts (1 block, 512 thr) -----------
__global__ void k2_scan(const int* __restrict__ ghist,
                        int* __restrict__ base,
                        int* __restrict__ gcursor) {
    __shared__ int ls[512];
    const int t = threadIdx.x;
    int v = (t < NBUCK) ? ghist[t] : 0;
    ls[t] = v;
    __syncthreads();
    int x = v;
    for (int off = 1; off < 512; off <<= 1) {
        int y = (t >= off) ? ls[t - off] : 0;
        __syncthreads();
        x += y;
        ls[t] = x;
        __syncthreads();
    }
    if (t < NBUCK) {
        base[t]    = x - v;
        gcursor[t] = x - v;
    }
}

// ---- k3: LDS counting-sort by bucket + coalesced global sweep -------------
__global__ void __launch_bounds__(256)
k3_bucket(const int* __restrict__ src,
          const int* __restrict__ dst,
          int* __restrict__ gcursor,
          int* __restrict__ packed) {
    __shared__ int lh[512];                   // hist (padded to 512)
    __shared__ int lstart[512];               // local exclusive scan
    __shared__ int lbase[NBUCK];              // global reserved base
    __shared__ int lcur[NBUCK];               // local cursors
    __shared__ int lscan[256];
    __shared__ int sortv[KCAP];               // bucket-sorted packed edges
    __shared__ unsigned short sortb[KCAP];    // bucket id per sorted entry

    const int total4 = N_EDGES / 4;
    const int start4 = blockIdx.x * CHUNK4;
    const int end4   = min(total4, start4 + CHUNK4);
    const int t      = threadIdx.x;

    for (int i = t; i < 512; i += 256) lh[i] = 0;
    for (int i = t; i < NBUCK; i += 256) lcur[i] = 0;
    __syncthreads();
    // pass A: LDS histogram
    for (int i = start4 + t; i < end4; i += 256) {
        int4 d4 = reinterpret_cast<const int4*>(dst)[i];
        atomicAdd(&lh[d4.x >> 8], 1);
        atomicAdd(&lh[d4.y >> 8], 1);
        atomicAdd(&lh[d4.z >> 8], 1);
        atomicAdd(&lh[d4.w >> 8], 1);
    }
    __syncthreads();
    // scan 512 padded counters: thread t owns elements 2t, 2t+1
    const int v0 = lh[2 * t], v1 = lh[2 * t + 1];
    const int s  = v0 + v1;
    lscan[t] = s;
    __syncthreads();
    int x = s;
    for (int off = 1; off < 256; off <<= 1) {
        int y = (t >= off) ? lscan[t - off] : 0;
        __syncthreads();
        x += y;
        lscan[t] = x;
        __syncthreads();
    }
    lstart[2 * t]     = x - s;
    lstart[2 * t + 1] = x - s + v0;
    // reserve global space: one atomic per (block, non-empty bucket)
    for (int b = t; b < NBUCK; b += 256) {
        const int c = lh[b];
        lbase[b] = c ? atomicAdd(&gcursor[b], c) : 0;
    }
    __syncthreads();
    // pass B: counting-sort into LDS
    for (int i = start4 + t; i < end4; i += 256) {
        int4 d4 = reinterpret_cast<const int4*>(dst)[i];
        int4 s4 = reinterpret_cast<const int4*>(src)[i];
        int b, sl;
        b = d4.x >> 8; sl = lstart[b] + atomicAdd(&lcur[b], 1);
        sortv[sl] = s4.x | ((d4.x & 255) << 17); sortb[sl] = (unsigned short)b;
        b = d4.y >> 8; sl = lstart[b] + atomicAdd(&lcur[b], 1);
        sortv[sl] = s4.y | ((d4.y & 255) << 17); sortb[sl] = (unsigned short)b;
        b = d4.z >> 8; sl = lstart[b] + atomicAdd(&lcur[b], 1);
        sortv[sl] = s4.z | ((d4.z & 255) << 17); sortb[sl] = (unsigned short)b;
        b = d4.w >> 8; sl = lstart[b] + atomicAdd(&lcur[b], 1);
        sortv[sl] = s4.w | ((d4.w & 255) << 17); sortb[sl] = (unsigned short)b;
    }
    __syncthreads();
    // coalesced sweep: consecutive threads -> consecutive global addresses
    const int n = (end4 - start4) * 4;
    for (int j = t; j < n; j += 256) {
        const int b = sortb[j];
        packed[lbase[b] + (j - lstart[b])] = sortv[j];
    }
}

// ---- k4: fine CSR within each bucket, in place (unchanged from r13) -------
__global__ void __launch_bounds__(256)
k4_fine(const int* __restrict__ ghist,
        const int* __restrict__ base,
        int* __restrict__ packed,
        int* __restrict__ deg,
        int* __restrict__ offs) {
    __shared__ int lpk[CAP];
    __shared__ int lcnt[256];
    __shared__ int lscan[256];
    __shared__ int lcur[256];
    const int b  = blockIdx.x;
    const int t  = threadIdx.x;
    const int gb = base[b];
    int nb = ghist[b];
    if (nb > CAP) nb = CAP;

    lcnt[t] = 0;
    __syncthreads();
    for (int idx = t; idx < nb; idx += 256) {
        const int p = packed[gb + idx];
        lpk[idx] = p;
        atomicAdd(&lcnt[(p >> 17) & 255], 1);
    }
    __syncthreads();
    lscan[t] = lcnt[t];
    __syncthreads();
    int x = lcnt[t];
    for (int off = 1; off < 256; off <<= 1) {
        int y = (t >= off) ? lscan[t - off] : 0;
        __syncthreads();
        x += y;
        lscan[t] = x;
        __syncthreads();
    }
    const int excl = x - lcnt[t];
    const int node = (b << 8) + t;
    if (node < N_NODES) {
        deg[node]  = lcnt[t];
        offs[node] = gb + excl;
    }
    lcur[t] = excl;
    __syncthreads();
    for (int idx = t; idx < nb; idx += 256) {
        const int p    = lpk[idx];
        const int slot = atomicAdd(&lcur[(p >> 17) & 255], 1);
        packed[gb + slot] = p & 0x1FFFF;
    }
}

// ---- k5: pull aggregation, 8 independent load chains ----------------------
__global__ void __launch_bounds__(256)
aggregate(const float* __restrict__ feat,
          const int*   __restrict__ edge_list,
          const int*   __restrict__ offs,
          const int*   __restrict__ deg,
          float*       __restrict__ out) {
    const size_t gtid = (size_t)blockIdx.x * blockDim.x + threadIdx.x;
    const int node = (int)(gtid >> 5);
    const int lane = threadIdx.x & 31;
    if (node >= N_NODES) return;

    const int base = offs[node];
    const int d    = deg[node];
    const size_t col = (size_t)lane * 4;

    float4 acc[8];
    #pragma unroll
    for (int k = 0; k < 8; ++k) acc[k] = make_float4(0.f, 0.f, 0.f, 0.f);

    int j = 0;
    for (; j + 7 < d; j += 8) {               // 8 loads in flight / lane
        int sid[8];
        #pragma unroll
        for (int k = 0; k < 8; ++k) sid[k] = edge_list[base + j + k];
        float4 f[8];
        #pragma unroll
        for (int k = 0; k < 8; ++k)
            f[k] = *reinterpret_cast<const float4*>(
                feat + (size_t)sid[k] * D_FEAT + col);
        #pragma unroll
        for (int k = 0; k < 8; ++k) {
            acc[k].x += f[k].x; acc[k].y += f[k].y;
            acc[k].z += f[k].z; acc[k].w += f[k].w;
        }
    }
    for (; j < d; ++j) {
        const int s0 = edge_list[base + j];
        const float4 a = *reinterpret_cast<const float4*>(
            feat + (size_t)s0 * D_FEAT + col);
        acc[0].x += a.x; acc[0].y += a.y; acc[0].z += a.z; acc[0].w += a.w;
    }
    #pragma unroll
    for (int k = 1; k < 8; ++k) {
        acc[0].x += acc[k].x; acc[0].y += acc[k].y;
        acc[0].z += acc[k].z; acc[0].w += acc[k].w;
    }
    const float inv = 1.0f / (float)max(d, 1);
    float4 r;
    r.x = acc[0].x * inv; r.y = acc[0].y * inv;
    r.z = acc[0].z * inv; r.w = acc[0].w * inv;
    *reinterpret_cast<float4*>(out + (size_t)node * D_FEAT + col) = r;
}

// ===========================================================================
// Fallback (atomic scatter) — only if ws_size is too small (never observed)
// ===========================================================================
__global__ void zero_out_deg(float* __restrict__ out, float* __restrict__ deg) {
    const size_t total4 = (size_t)N_NODES * D_FEAT / 4;
    size_t tid    = (size_t)blockIdx.x * blockDim.x + threadIdx.x;
    size_t stride = (size_t)gridDim.x * blockDim.x;
    float4 z = make_float4(0.f, 0.f, 0.f, 0.f);
    for (size_t i = tid; i < total4; i += stride)
        reinterpret_cast<float4*>(out)[i] = z;
    for (size_t i = tid; i < N_NODES; i += stride)
        deg[i] = 0.f;
}

__global__ void scatter_atomic(const float* __restrict__ feat,
                               const int*   __restrict__ src,
                               const int*   __restrict__ dst,
                               float*       __restrict__ out,
                               float*       __restrict__ deg) {
    const size_t total  = (size_t)N_EDGES * 32;
    size_t tid    = (size_t)blockIdx.x * blockDim.x + threadIdx.x;
    size_t stride = (size_t)gridDim.x * blockDim.x;
    for (size_t i = tid; i < total; i += stride) {
        const int e = (int)(i >> 5);
        const int c = (int)(i & 31);
        const int s = src[e];
        const int d = dst[e];
        float4 v = reinterpret_cast<const float4*>(feat + (size_t)s * D_FEAT)[c];
        float* o = out + (size_t)d * D_FEAT + (size_t)c * 4;
        unsafeAtomicAdd(o + 0, v.x);
        unsafeAtomicAdd(o + 1, v.y);
        unsafeAtomicAdd(o + 2, v.z);
        unsafeAtomicAdd(o + 3, v.w);
        if (c == 0) unsafeAtomicAdd(deg + d, 1.0f);
    }
}

__global__ void div_mean(float* __restrict__ out, const float* __restrict__ deg) {
    const size_t total4 = (size_t)N_NODES * D_FEAT / 4;
    size_t tid    = (size_t)blockIdx.x * blockDim.x + threadIdx.x;
    size_t stride = (size_t)gridDim.x * blockDim.x;
    for (size_t i = tid; i < total4; i += stride) {
        const float inv = 1.0f / fmaxf(deg[i >> 5], 1.0f);
        float4 v = reinterpret_cast<float4*>(out)[i];
        v.x *= inv; v.y *= inv; v.z *= inv; v.w *= inv;
        reinterpret_cast<float4*>(out)[i] = v;
    }
}

// ===========================================================================
extern "C" void kernel_launch(void* const* d_in, const int* in_sizes, int n_in,
                              void* d_out, int out_size, void* d_ws, size_t ws_size,
                              hipStream_t stream) {
    const float* feat = (const float*)d_in[0];
    const int*   src  = (const int*)d_in[1];
    const int*   dst  = (const int*)d_in[2];
    float* out = (float*)d_out;

    // Workspace (ints): ghist[512] | base[512] | gcursor[512] | deg[N] |
    //                   offs[N] | packed[E]  (~6.9 MiB)
    const size_t need = ((size_t)1536 + 2 * N_NODES + N_EDGES) * sizeof(int);

    if (ws_size >= need) {
        int* ghist   = (int*)d_ws;
        int* base    = ghist   + 512;
        int* gcursor = base    + 512;
        int* deg     = gcursor + 512;
        int* offs    = deg     + N_NODES;
        int* packed  = offs    + N_NODES;    // doubles as final edge_list

        hipMemsetAsync(ghist, 0, NBUCK * sizeof(int), stream);
        k1_coarse_hist<<<256,   256, 0, stream>>>(dst, ghist);
        k2_scan       <<<1,     512, 0, stream>>>(ghist, base, gcursor);
        k3_bucket     <<<256,   256, 0, stream>>>(src, dst, gcursor, packed);
        k4_fine       <<<NBUCK, 256, 0, stream>>>(ghist, base, packed, deg, offs);
        aggregate     <<<12500, 256, 0, stream>>>(feat, packed, offs, deg, out);
    } else {
        float* fdeg = (float*)d_ws;
        zero_out_deg  <<<2048, 256, 0, stream>>>(out, fdeg);
        scatter_atomic<<<8192, 256, 0, stream>>>(feat, src, dst, out, fdeg);
        div_mean      <<<2048, 256, 0, stream>>>(out, fdeg);
    }
}